// Round 1
// baseline (35.542 us; speedup 1.0000x reference)
//
#include <hip/hip_runtime.h>

// NcutLoss: N=4, K=8, C=3, H=W=1024, S=1000, R=5, P=81 disk points.
// loss = N*K - sum_{n,k} num[n,k]/den[n,k]
//   num[n,k] = sum_{s,p} wgt[n,s,p]*q[n,k,s,p]*pc[n,k,s]
//   den[n,k] = sum_s pc[n,k,s] * sum_p wgt[n,s,p]
//   wgt = exp(-d2/SIGMA_I^2 - (di^2+dj^2)/SIGMA_X^2), d2 = sum_c (img_n-img_c)^2

constexpr int P = 81;
constexpr int HH = 1024, WW = 1024;
constexpr size_t HW = (size_t)HH * WW;
constexpr int NN = 4, KK = 8, CC = 3;
constexpr float INV_SI2 = 1.0f / 100.0f;  // 1/SIGMA_I^2
constexpr float INV_SX2 = 1.0f / 16.0f;   // 1/SIGMA_X^2

// Disk offsets, row-major over di=-5..5 (order irrelevant: all sums over p).
__device__ __constant__ signed char c_di[P] = {
    -5,
    -4,-4,-4,-4,-4,-4,-4,
    -3,-3,-3,-3,-3,-3,-3,-3,-3,
    -2,-2,-2,-2,-2,-2,-2,-2,-2,
    -1,-1,-1,-1,-1,-1,-1,-1,-1,
     0, 0, 0, 0, 0, 0, 0, 0, 0, 0, 0,
     1, 1, 1, 1, 1, 1, 1, 1, 1,
     2, 2, 2, 2, 2, 2, 2, 2, 2,
     3, 3, 3, 3, 3, 3, 3, 3, 3,
     4, 4, 4, 4, 4, 4, 4,
     5
};
__device__ __constant__ signed char c_dj[P] = {
     0,
    -3,-2,-1, 0, 1, 2, 3,
    -4,-3,-2,-1, 0, 1, 2, 3, 4,
    -4,-3,-2,-1, 0, 1, 2, 3, 4,
    -4,-3,-2,-1, 0, 1, 2, 3, 4,
    -5,-4,-3,-2,-1, 0, 1, 2, 3, 4, 5,
    -4,-3,-2,-1, 0, 1, 2, 3, 4,
    -4,-3,-2,-1, 0, 1, 2, 3, 4,
    -4,-3,-2,-1, 0, 1, 2, 3, 4,
    -3,-2,-1, 0, 1, 2, 3,
     0
};

__global__ void ncut_zero(float* __restrict__ acc) {
    acc[threadIdx.x] = 0.0f;  // 64 floats: num[32], den[32]
}

__global__ __launch_bounds__(256) void ncut_accum(
    const float* __restrict__ pred,   // (N,K,H,W)
    const float* __restrict__ imgs,   // (N,C,H,W)
    const long long* __restrict__ hs, // (S,)
    const long long* __restrict__ wsm,// (S,)
    float* __restrict__ acc,          // 64 floats
    int S)
{
    __shared__ float lnum[KK];
    __shared__ float lden[KK];
    const int tid  = threadIdx.x;
    const int lane = tid & 63;
    const int wave = tid >> 6;
    if (tid < KK) { lnum[tid] = 0.0f; lden[tid] = 0.0f; }
    __syncthreads();

    const int n = blockIdx.y;
    const int s = blockIdx.x * 4 + wave;
    if (s < S) {
        const int h = (int)hs[s] + 5;
        const int w = (int)wsm[s] + 5;
        const float* img_n = imgs + (size_t)n * CC * HW;
        const size_t coff = (size_t)h * WW + w;
        const float c0 = img_n[coff];
        const float c1 = img_n[HW + coff];
        const float c2 = img_n[2 * HW + coff];
        const float* pn = pred + (size_t)n * KK * HW;

        float qw[KK] = {0.f,0.f,0.f,0.f,0.f,0.f,0.f,0.f};
        float wsum = 0.0f;

        #pragma unroll
        for (int rep = 0; rep < 2; ++rep) {
            const int p = lane + rep * 64;
            if (p < P) {
                const int di = (int)c_di[p];
                const int dj = (int)c_dj[p];
                const size_t off = (size_t)(h + di) * WW + (w + dj);
                const float d0 = img_n[off]          - c0;
                const float d1 = img_n[HW + off]     - c1;
                const float d2 = img_n[2 * HW + off] - c2;
                const float r2 = (float)(di * di + dj * dj);
                const float wgt = __expf(-((d0*d0 + d1*d1 + d2*d2) * INV_SI2
                                           + r2 * INV_SX2));
                wsum += wgt;
                const float* qb = pn + off;
                #pragma unroll
                for (int k = 0; k < KK; ++k)
                    qw[k] += wgt * qb[(size_t)k * HW];
            }
        }

        // 64-lane butterfly reduction of 9 values; all lanes end with totals.
        #pragma unroll
        for (int off = 32; off; off >>= 1) {
            wsum += __shfl_xor(wsum, off);
            #pragma unroll
            for (int k = 0; k < KK; ++k)
                qw[k] += __shfl_xor(qw[k], off);
        }

        if (lane == 0) {
            const float* pc = pn + coff;
            #pragma unroll
            for (int k = 0; k < KK; ++k) {
                const float pv = pc[(size_t)k * HW];
                atomicAdd(&lnum[k], pv * qw[k]);
                atomicAdd(&lden[k], pv * wsum);
            }
        }
    }
    __syncthreads();
    if (tid < KK) {
        atomicAdd(&acc[n * KK + tid],               lnum[tid]);
        atomicAdd(&acc[NN * KK + n * KK + tid],     lden[tid]);
    }
}

__global__ void ncut_final(const float* __restrict__ acc, float* __restrict__ out) {
    const int tid = threadIdx.x;  // 64 threads
    float r = 0.0f;
    if (tid < NN * KK) r = acc[tid] / acc[NN * KK + tid];
    #pragma unroll
    for (int off = 32; off; off >>= 1)
        r += __shfl_xor(r, off);
    if (tid == 0) out[0] = (float)(NN * KK) - r;
}

extern "C" void kernel_launch(void* const* d_in, const int* in_sizes, int n_in,
                              void* d_out, int out_size, void* d_ws, size_t ws_size,
                              hipStream_t stream) {
    const float* pred     = (const float*)d_in[0];
    const float* imgs     = (const float*)d_in[1];
    const long long* hs   = (const long long*)d_in[2];
    const long long* wsm  = (const long long*)d_in[3];
    const int S = in_sizes[2];
    float* acc = (float*)d_ws;   // 64 floats
    float* out = (float*)d_out;

    ncut_zero<<<1, 64, 0, stream>>>(acc);
    dim3 grid((S + 3) / 4, NN);
    ncut_accum<<<grid, 256, 0, stream>>>(pred, imgs, hs, wsm, acc, S);
    ncut_final<<<1, 64, 0, stream>>>(acc, out);
}

// Round 2
// 28.445 us; speedup vs baseline: 1.2495x; 1.2495x over previous
//
#include <hip/hip_runtime.h>

// NcutLoss: N=4, K=8, C=3, H=W=1024, S=1000, R=5, P=81 disk points.
// loss = N*K - sum_{n,k} num[n,k]/den[n,k]
//   num[n,k] = sum_{s,p} wgt[n,s,p]*q[n,k,s,p]*pc[n,k,s]
//   den[n,k] = sum_s pc[n,k,s] * sum_p wgt[n,s,p]
//   wgt = exp(-d2/SIGMA_I^2 - (di^2+dj^2)/SIGMA_X^2), d2 = sum_c (img_n-img_c)^2
//
// R1 change: striped global accumulators (64 stripes x 64 floats in d_ws)
// to break same-address atomic serialization (250 blocks/address -> ~4).

constexpr int P = 81;
constexpr int HH = 1024, WW = 1024;
constexpr size_t HW = (size_t)HH * WW;
constexpr int NN = 4, KK = 8, CC = 3;
constexpr int NSTRIPE = 64;               // accumulator copies
constexpr float INV_SI2 = 1.0f / 100.0f;  // 1/SIGMA_I^2
constexpr float INV_SX2 = 1.0f / 16.0f;   // 1/SIGMA_X^2

// Disk offsets, row-major over di=-5..5 (order irrelevant: all sums over p).
__device__ __constant__ signed char c_di[P] = {
    -5,
    -4,-4,-4,-4,-4,-4,-4,
    -3,-3,-3,-3,-3,-3,-3,-3,-3,
    -2,-2,-2,-2,-2,-2,-2,-2,-2,
    -1,-1,-1,-1,-1,-1,-1,-1,-1,
     0, 0, 0, 0, 0, 0, 0, 0, 0, 0, 0,
     1, 1, 1, 1, 1, 1, 1, 1, 1,
     2, 2, 2, 2, 2, 2, 2, 2, 2,
     3, 3, 3, 3, 3, 3, 3, 3, 3,
     4, 4, 4, 4, 4, 4, 4,
     5
};
__device__ __constant__ signed char c_dj[P] = {
     0,
    -3,-2,-1, 0, 1, 2, 3,
    -4,-3,-2,-1, 0, 1, 2, 3, 4,
    -4,-3,-2,-1, 0, 1, 2, 3, 4,
    -4,-3,-2,-1, 0, 1, 2, 3, 4,
    -5,-4,-3,-2,-1, 0, 1, 2, 3, 4, 5,
    -4,-3,-2,-1, 0, 1, 2, 3, 4,
    -4,-3,-2,-1, 0, 1, 2, 3, 4,
    -4,-3,-2,-1, 0, 1, 2, 3, 4,
    -3,-2,-1, 0, 1, 2, 3,
     0
};

__global__ void ncut_zero(float* __restrict__ acc) {
    const int i = blockIdx.x * blockDim.x + threadIdx.x;
    if (i < NSTRIPE * 64) acc[i] = 0.0f;
}

__global__ __launch_bounds__(256) void ncut_accum(
    const float* __restrict__ pred,   // (N,K,H,W)
    const float* __restrict__ imgs,   // (N,C,H,W)
    const long long* __restrict__ hs, // (S,)
    const long long* __restrict__ wsm,// (S,)
    float* __restrict__ acc,          // NSTRIPE x 64 floats
    int S)
{
    __shared__ float lnum[KK];
    __shared__ float lden[KK];
    const int tid  = threadIdx.x;
    const int lane = tid & 63;
    const int wave = tid >> 6;
    if (tid < KK) { lnum[tid] = 0.0f; lden[tid] = 0.0f; }
    __syncthreads();

    const int n = blockIdx.y;
    const int s = blockIdx.x * 4 + wave;
    if (s < S) {
        const int h = (int)hs[s] + 5;
        const int w = (int)wsm[s] + 5;
        const float* img_n = imgs + (size_t)n * CC * HW;
        const size_t coff = (size_t)h * WW + w;
        const float c0 = img_n[coff];
        const float c1 = img_n[HW + coff];
        const float c2 = img_n[2 * HW + coff];
        const float* pn = pred + (size_t)n * KK * HW;

        float qw[KK] = {0.f,0.f,0.f,0.f,0.f,0.f,0.f,0.f};
        float wsum = 0.0f;

        #pragma unroll
        for (int rep = 0; rep < 2; ++rep) {
            const int p = lane + rep * 64;
            if (p < P) {
                const int di = (int)c_di[p];
                const int dj = (int)c_dj[p];
                const size_t off = (size_t)(h + di) * WW + (w + dj);
                const float d0 = img_n[off]          - c0;
                const float d1 = img_n[HW + off]     - c1;
                const float d2 = img_n[2 * HW + off] - c2;
                const float r2 = (float)(di * di + dj * dj);
                const float wgt = __expf(-((d0*d0 + d1*d1 + d2*d2) * INV_SI2
                                           + r2 * INV_SX2));
                wsum += wgt;
                const float* qb = pn + off;
                #pragma unroll
                for (int k = 0; k < KK; ++k)
                    qw[k] += wgt * qb[(size_t)k * HW];
            }
        }

        // 64-lane butterfly reduction of 9 values; all lanes end with totals.
        #pragma unroll
        for (int off = 32; off; off >>= 1) {
            wsum += __shfl_xor(wsum, off);
            #pragma unroll
            for (int k = 0; k < KK; ++k)
                qw[k] += __shfl_xor(qw[k], off);
        }

        if (lane == 0) {
            const float* pc = pn + coff;
            #pragma unroll
            for (int k = 0; k < KK; ++k) {
                const float pv = pc[(size_t)k * HW];
                atomicAdd(&lnum[k], pv * qw[k]);
                atomicAdd(&lden[k], pv * wsum);
            }
        }
    }
    __syncthreads();
    // Striped global accumulation: stripe per block -> ~4-way contention.
    if (tid < KK) {
        float* st = acc + (size_t)(blockIdx.x & (NSTRIPE - 1)) * 64;
        atomicAdd(&st[n * KK + tid],      lnum[tid]);
        atomicAdd(&st[32 + n * KK + tid], lden[tid]);
    }
}

__global__ void ncut_final(const float* __restrict__ acc, float* __restrict__ out) {
    const int tid = threadIdx.x;  // 64 threads: tid<32 num slots, tid>=32 den slots
    float v = 0.0f;
    #pragma unroll 8
    for (int st = 0; st < NSTRIPE; ++st)
        v += acc[st * 64 + tid];
    const float den = __shfl_xor(v, 32);     // lane t<32 gets matching den
    float r = (tid < 32) ? v / den : 0.0f;
    #pragma unroll
    for (int off = 32; off; off >>= 1)
        r += __shfl_xor(r, off);
    if (tid == 0) out[0] = (float)(NN * KK) - r;
}

extern "C" void kernel_launch(void* const* d_in, const int* in_sizes, int n_in,
                              void* d_out, int out_size, void* d_ws, size_t ws_size,
                              hipStream_t stream) {
    const float* pred     = (const float*)d_in[0];
    const float* imgs     = (const float*)d_in[1];
    const long long* hs   = (const long long*)d_in[2];
    const long long* wsm  = (const long long*)d_in[3];
    const int S = in_sizes[2];
    float* acc = (float*)d_ws;   // NSTRIPE * 64 floats = 16 KB
    float* out = (float*)d_out;

    ncut_zero<<<(NSTRIPE * 64 + 255) / 256, 256, 0, stream>>>(acc);
    dim3 grid((S + 3) / 4, NN);
    ncut_accum<<<grid, 256, 0, stream>>>(pred, imgs, hs, wsm, acc, S);
    ncut_final<<<1, 64, 0, stream>>>(acc, out);
}